// Round 9
// baseline (307.171 us; speedup 1.0000x reference)
//
#include <hip/hip_runtime.h>
#include <hip/hip_bf16.h>

#define N_    2
#define T_    7
#define C_    96
#define H_    96
#define W_    96
#define HW_   9216
#define HEAD_ 4
#define HD_   24
#define C3_   288
#define P_    16           // pixels per block: grid 1152, 256 threads
#define QP_   100          // padded row stride for q/k tiles (mult of 4 -> 16B-aligned)
#define CATP_ 292          // padded row stride for cat tile (mult of 4)
#define NBLK_ (N_ * (HW_ / P_))   // 1152
#define PLANES_ 14         // n*t
#define CHUNK_  48         // transpose chunk: tile 18.4 KB -> 8 blocks/CU
#define NCHUNK_ 192        // 9216/48
#define TBLK_ (PLANES_ * NCHUNK_) // 2688 transpose blocks per array

typedef unsigned int u32;

__device__ __forceinline__ float bits2f(u32 b) {
    union { u32 u; float f; } x; x.u = b; return x.f;
}

__device__ __forceinline__ unsigned short f2bf(float f) {
    union { __hip_bfloat16 h; unsigned short s; } u;
    u.h = __float2bfloat16(f);
    return u.s;
}

template<bool BF16>
__device__ __forceinline__ float ld1(const void* p, int i) {
    if constexpr (BF16) return bits2f(((u32)((const unsigned short*)p)[i]) << 16);
    else                return ((const float*)p)[i];
}

// load 4 consecutive elements starting at i (i % 4 == 0)
template<bool BF16>
__device__ __forceinline__ void ld4w(const void* p, int i, float w[4]) {
    if constexpr (BF16) {
        const uint2 u = ((const uint2*)p)[i >> 2];
        w[0] = bits2f(u.x << 16);
        w[1] = bits2f(u.x & 0xFFFF0000u);
        w[2] = bits2f(u.y << 16);
        w[3] = bits2f(u.y & 0xFFFF0000u);
    } else {
        const float4 v = *((const float4*)((const float*)p + i));
        w[0] = v.x; w[1] = v.y; w[2] = v.z; w[3] = v.w;
    }
}

template<bool BF16>
__device__ __forceinline__ void st1(void* p, int i, float v) {
    if constexpr (BF16) ((unsigned short*)p)[i] = f2bf(v);
    else                ((float*)p)[i] = v;
}

// store 4 consecutive elements starting at i (i % 4 == 0)
template<bool BF16>
__device__ __forceinline__ void st4w(void* p, int i, const float v[4]) {
    if constexpr (BF16) {
        uint2 w;
        w.x = (u32)f2bf(v[0]) | ((u32)f2bf(v[1]) << 16);
        w.y = (u32)f2bf(v[2]) | ((u32)f2bf(v[3]) << 16);
        ((uint2*)p)[i >> 2] = w;
    } else {
        *((float4*)((float*)p + i)) = make_float4(v[0], v[1], v[2], v[3]);
    }
}

// ---- per-block dtype detect: deterministic, same rule everywhere ----
__device__ __forceinline__ bool block_detect_bf16(const u32* __restrict__ w,
                                                  int tid, int* s_flag) {
    if (tid < 64) {
        u32 x = w[tid];
        u32 f = x & 0x7FFFu;
        int inwin = (f >= 0x3A00u) && (f <= 0x4200u);
        unsigned long long m = __ballot(inwin);
        if (tid == 0) *s_flag = (__popcll(m) >= 40) ? 1 : 0;
    }
    __syncthreads();
    return *s_flag != 0;
}

// ---- (c,hw) -> (hw,c) transpose chunk (48 px), bit-exact copy, XOR-swizzled LDS ----
// Tile pixel-major [48][96], col-group swizzle g = (ch>>2) ^ ((row>>2)&7).
template<bool BF16>
__device__ __forceinline__ void transp_swz(const void* __restrict__ src,
                                           void* __restrict__ dst,
                                           int pl, int x0, int tid, char* raw) {
    if constexpr (BF16) {
        unsigned short* tile = (unsigned short*)raw;      // [48][96] swizzled
        const unsigned short* s = (const unsigned short*)src;
        unsigned short* d = (unsigned short*)dst;
        for (int i = tid; i < C_ * (CHUNK_ / 4); i += 256) {   // 1152
            int ch = i / 12, xq = i - ch * 12;
            const ushort4 v = *((const ushort4*)(s + (pl * C_ + ch) * HW_ + x0 + 4 * xq));
            int g = (ch >> 2) ^ (xq & 7);                  // (row>>2)&7 == xq&7 for rows 4xq+k
            int chl = ch & 3;
            tile[(4 * xq + 0) * 96 + 4 * g + chl] = v.x;
            tile[(4 * xq + 1) * 96 + 4 * g + chl] = v.y;
            tile[(4 * xq + 2) * 96 + 4 * g + chl] = v.z;
            tile[(4 * xq + 3) * 96 + 4 * g + chl] = v.w;
        }
        __syncthreads();
        for (int i = tid; i < CHUNK_ * (C_ / 4); i += 256) {   // 1152
            int p = i / 24, cq = i - p * 24;
            int g = cq ^ ((p >> 2) & 7);
            const ushort4 v = *((const ushort4*)&tile[p * 96 + 4 * g]);
            *((ushort4*)(d + (pl * HW_ + x0 + p) * C_ + 4 * cq)) = v;
        }
    } else {
        float* tile = (float*)raw;                         // [48][96] swizzled, 18.4 KB
        const float* s = (const float*)src;
        float* d = (float*)dst;
        for (int i = tid; i < C_ * (CHUNK_ / 4); i += 256) {
            int ch = i / 12, xq = i - ch * 12;
            const float4 v = *((const float4*)(s + (pl * C_ + ch) * HW_ + x0 + 4 * xq));
            int g = (ch >> 2) ^ (xq & 7);
            int chl = ch & 3;
            tile[(4 * xq + 0) * 96 + 4 * g + chl] = v.x;
            tile[(4 * xq + 1) * 96 + 4 * g + chl] = v.y;
            tile[(4 * xq + 2) * 96 + 4 * g + chl] = v.z;
            tile[(4 * xq + 3) * 96 + 4 * g + chl] = v.w;
        }
        __syncthreads();
        for (int i = tid; i < CHUNK_ * (C_ / 4); i += 256) {
            int p = i / 24, cq = i - p * 24;
            int g = cq ^ ((p >> 2) & 7);
            const float4 v = *((const float4*)&tile[p * 96 + 4 * g]);
            *((float4*)(d + (pl * HW_ + x0 + p) * C_ + 4 * cq)) = v;
        }
    }
}

__global__ __launch_bounds__(256) void transp_kernel(
    const void* __restrict__ a0, const void* __restrict__ a1,
    const void* __restrict__ a2, const void* __restrict__ a3,
    void* __restrict__ dstb, unsigned long long szb,
    const u32* __restrict__ detect_src)
{
    __shared__ __align__(16) char raw[CHUNK_ * 96 * 4];
    __shared__ int s_flag;
    const int arr = blockIdx.y;
    const void* src = (arr == 0) ? a0 : (arr == 1) ? a1 : (arr == 2) ? a2 : a3;
    void* dst = (char*)dstb + (unsigned long long)arr * szb;
    const int tid = threadIdx.x;
    const int pl = blockIdx.x / NCHUNK_;
    const int x0 = (blockIdx.x - pl * NCHUNK_) * CHUNK_;
    const bool bf = block_detect_bf16(detect_src, tid, &s_flag);
    if (bf) transp_swz<true >(src, dst, pl, x0, tid, raw);
    else    transp_swz<false>(src, dst, pl, x0, tid, raw);
}

// ====================== argmax body: register-prefetch pipelined k-gather ======================
// Same loads, same LDS contents, same FP chains as the verified round-8 body;
// only the ISSUE timing of the frame-(t+1) gather changes (overlaps frame-t compute).
template<bool BF16, bool TGB>
__device__ __forceinline__ void argmax_body(
    const void* __restrict__ curr, const void* __restrict__ loc,
    const void* __restrict__ kT,
    float* __restrict__ ws_best, int* __restrict__ ws_gbase,
    float* s_u, int (*s_lin)[P_], float (*s_red)[8],
    float (*s_best)[HEAD_], int (*s_bidx)[HEAD_], float* s_inv)
{
#define S_Q(pp, ch)  s_u[(pp) * QP_ + (ch)]
#define S_K(pp, ch)  s_u[P_ * QP_ + (pp) * QP_ + (ch)]
    const int tid = threadIdx.x;
    const int b  = blockIdx.x;
    const int nn = b / (HW_ / P_);
    const int p0 = (b - nn * (HW_ / P_)) * P_;

    if (tid < T_ * P_) {
        int t = tid / P_, pp = tid - t * P_;
        int p = p0 + pp;
        float x = ld1<BF16>(loc, (nn * 2 * T_ + 2 * t    ) * HW_ + p);
        float y = ld1<BF16>(loc, (nn * 2 * T_ + 2 * t + 1) * HW_ + p);
        float gx = 2.0f * x / 95.0f - 1.0f;
        float gy = 2.0f * y / 95.0f - 1.0f;
        float fx = (gx + 1.0f) * 0.5f * 95.0f;
        float fy = (gy + 1.0f) * 0.5f * 95.0f;
        float ix = rintf(fx), iy = rintf(fy);     // round-half-even == jnp.round
        bool v = (ix >= 0.0f) && (ix <= 95.0f) && (iy >= 0.0f) && (iy <= 95.0f);
        s_lin[t][pp] = v ? ((int)iy * W_ + (int)ix) : -1;
    }
    if (tid >= 128 && tid < 128 + P_ * HEAD_) {
        int q = tid - 128;
        s_best[q >> 2][q & 3] = -3.0e38f; s_bidx[q >> 2][q & 3] = 0;
    }

    for (int i = tid; i < C_ * (P_ / 4); i += 256) {
        int ch = i >> 2, pq = i & 3;
        float w[4];
        ld4w<BF16>(curr, (nn * C_ + ch) * HW_ + p0 + 4 * pq, w);
        S_Q(4 * pq + 0, ch) = w[0]; S_Q(4 * pq + 1, ch) = w[1];
        S_Q(4 * pq + 2, ch) = w[2]; S_Q(4 * pq + 3, ch) = w[3];
    }
    __syncthreads();

    if (tid < P_ * 8) {
        int pp = tid >> 3, j = tid & 7;
        float s = 0.f;
        #pragma unroll
        for (int k = 0; k < 12; ++k) { float v = S_Q(pp, j * 12 + k); s += v * v; }
        s_red[pp][j] = s;
    }
    __syncthreads();
    if (tid < P_) {
        float s = 0.f;
        #pragma unroll
        for (int j = 0; j < 8; ++j) s += s_red[tid][j];
        s_inv[tid] = 1.0f / fmaxf(sqrtf(s), 1e-12f);
    }
    __syncthreads();
    for (int i = tid; i < C_ * P_; i += 256) {
        int pp = i & (P_ - 1), ch = i >> 4;
        S_Q(pp, ch) *= s_inv[pp];
    }

    // item mapping (identical to the old strided loop): item0 = tid, item1 = tid+256 (tid<128)
    const int pp0 = tid / 24,        j0 = tid - pp0 * 24;
    const int pp1 = (tid + 256) / 24, j1 = (tid + 256) - pp1 * 24;
    const bool has1 = (tid < 128);

    float4 ka0, ka1;
    {   // prime frame 0
        int lin = s_lin[0][pp0];
        float w[4] = {0.f, 0.f, 0.f, 0.f};
        if (lin >= 0) ld4w<BF16>(kT, ((nn * T_) * HW_ + lin) * C_ + 4 * j0, w);
        ka0 = make_float4(w[0], w[1], w[2], w[3]);
        if (has1) {
            int lin2 = s_lin[0][pp1];
            float w2[4] = {0.f, 0.f, 0.f, 0.f};
            if (lin2 >= 0) ld4w<BF16>(kT, ((nn * T_) * HW_ + lin2) * C_ + 4 * j1, w2);
            ka1 = make_float4(w2[0], w2[1], w2[2], w2[3]);
        }
    }

    for (int t = 0; t < T_; ++t) {
        __syncthreads();   // prev dots done reading S_K (t=0: q-scale done)
        *((float4*)&S_K(pp0, 4 * j0)) = ka0;
        if (has1) *((float4*)&S_K(pp1, 4 * j1)) = ka1;
        if (t + 1 < T_) {  // issue next frame's gather; latency overlaps compute below
            int lin = s_lin[t + 1][pp0];
            float w[4] = {0.f, 0.f, 0.f, 0.f};
            if (lin >= 0) ld4w<BF16>(kT, ((nn * T_ + t + 1) * HW_ + lin) * C_ + 4 * j0, w);
            ka0 = make_float4(w[0], w[1], w[2], w[3]);
            if (has1) {
                int lin2 = s_lin[t + 1][pp1];
                float w2[4] = {0.f, 0.f, 0.f, 0.f};
                if (lin2 >= 0) ld4w<BF16>(kT, ((nn * T_ + t + 1) * HW_ + lin2) * C_ + 4 * j1, w2);
                ka1 = make_float4(w2[0], w2[1], w2[2], w2[3]);
            }
        }
        __syncthreads();
        if (tid < P_ * 8) {
            int pp = tid >> 3, j = tid & 7;
            float s = 0.f;
            #pragma unroll
            for (int k = 0; k < 12; ++k) { float v = S_K(pp, j * 12 + k); s += v * v; }
            s_red[pp][j] = s;
        }
        __syncthreads();
        if (tid < P_) {
            float s = 0.f;
            #pragma unroll
            for (int j = 0; j < 8; ++j) s += s_red[tid][j];
            s_inv[tid] = 1.0f / fmaxf(sqrtf(s), 1e-12f);
        }
        __syncthreads();
        if (tid < P_ * HEAD_) {
            int pp = tid >> 2, h = tid & 3;
            float s = 0.f;
            #pragma unroll
            for (int dq = 0; dq < 6; ++dq) {
                const float4 kv = *((const float4*)&S_K(pp, h * HD_ + 4 * dq));
                const float4 qv = *((const float4*)&S_Q(pp, h * HD_ + 4 * dq));
                s += kv.x * qv.x; s += kv.y * qv.y; s += kv.z * qv.z; s += kv.w * qv.w;
            }
            s *= s_inv[pp];
            if (s > s_best[pp][h]) { s_best[pp][h] = s; s_bidx[pp][h] = t; }  // strict > == first-max
        }
    }
    if (tid < P_ * HEAD_) {
        int pp = tid >> 2, h = tid & 3;
        int bt = s_bidx[pp][h];
        int lin = s_lin[bt][pp];
        int g = (nn * HW_ + p0 + pp) * HEAD_ + h;
        ws_best[g] = s_best[pp][h];
        int gb;
        if (lin < 0)       gb = -1;
        else if (TGB)      gb = ((nn * T_ + bt) * HW_ + lin) * C_;   // transposed (hw,c) coords
        else               gb = (nn * T_ + bt) * C_ * HW_ + lin;     // original (c,hw) coords
        ws_gbase[g] = gb;
    }
#undef S_Q
#undef S_K
}

// standalone argmax (kT-only fallback mode)
template<bool TGB>
__global__ __launch_bounds__(256, 8) void argmax_kernel(
    const void* __restrict__ curr, const void* __restrict__ loc,
    const void* __restrict__ kT,
    float* __restrict__ ws_best, int* __restrict__ ws_gbase)
{
    __shared__ __align__(16) float s_u[2 * P_ * QP_];   // q | k  (12.8 KB)
    __shared__ int   s_lin[T_][P_];
    __shared__ float s_red[P_][8];
    __shared__ float s_best[P_][HEAD_];
    __shared__ int   s_bidx[P_][HEAD_];
    __shared__ float s_inv[P_];
    __shared__ int   s_flag;
    const bool bf = block_detect_bf16((const u32*)curr, threadIdx.x, &s_flag);
    if (bf) argmax_body<true , TGB>(curr, loc, kT, ws_best, ws_gbase, s_u, s_lin, s_red, s_best, s_bidx, s_inv);
    else    argmax_body<false, TGB>(curr, loc, kT, ws_best, ws_gbase, s_u, s_lin, s_red, s_best, s_bidx, s_inv);
}

// ====================== FUSED: argmax blocks + s1/s2/s3-transpose blocks ======================
__global__ __launch_bounds__(256, 8) void fused_kernel(
    const void* __restrict__ curr, const void* __restrict__ loc,
    const void* __restrict__ kT,
    const void* __restrict__ s1, const void* __restrict__ s2,
    const void* __restrict__ s3,
    void* __restrict__ s123T, unsigned long long szb,
    float* __restrict__ ws_best, int* __restrict__ ws_gbase)
{
    __shared__ __align__(16) char raw[CHUNK_ * 96 * 4];   // 18.4 KB: transp tile / argmax overlay
    __shared__ int s_flag;
    const int tid = threadIdx.x;
    const bool bf = block_detect_bf16((const u32*)curr, tid, &s_flag);
    const int bx = blockIdx.x;
    if (bx < NBLK_) {
        float* s_u            = (float*)raw;                        // 12800 B
        int   (*s_lin)[P_]    = (int(*)[P_])   (raw + 12800);       // 448
        float (*s_red)[8]     = (float(*)[8])  (raw + 13248);       // 512
        float (*s_best)[HEAD_]= (float(*)[HEAD_])(raw + 13760);     // 256
        int   (*s_bidx)[HEAD_]= (int(*)[HEAD_]) (raw + 14016);      // 256
        float* s_inv          = (float*)(raw + 14272);              // 64
        if (bf) argmax_body<true , true>(curr, loc, kT, ws_best, ws_gbase,
                                         s_u, s_lin, s_red, s_best, s_bidx, s_inv);
        else    argmax_body<false, true>(curr, loc, kT, ws_best, ws_gbase,
                                         s_u, s_lin, s_red, s_best, s_bidx, s_inv);
    } else {
        int t = bx - NBLK_;
        int arr = t / TBLK_;
        int bxx = t - arr * TBLK_;
        const void* src = (arr == 0) ? s1 : (arr == 1) ? s2 : s3;
        void* dst = (char*)s123T + (unsigned long long)arr * szb;
        int pl = bxx / NCHUNK_;
        int x0 = (bxx - pl * NCHUNK_) * CHUNK_;
        if (bf) transp_swz<true >(src, dst, pl, x0, tid, raw);
        else    transp_swz<false>(src, dst, pl, x0, tid, raw);
    }
}

// ====================== KERNEL B: cat gather + GEMVs (round-8 verbatim) ======================
template<bool BF16, bool TRANS>
__device__ __forceinline__ void catgemv_body(
    const void* __restrict__ anchor, const void* __restrict__ s1,
    const void* __restrict__ s2, const void* __restrict__ s3,
    const void* __restrict__ pw, const void* __restrict__ pb,
    const void* __restrict__ fw, const void* __restrict__ fb,
    void* __restrict__ outp,
    const float* __restrict__ ws_best, const int* __restrict__ ws_gbase,
    float* s_u, float (*s_mid)[QP_], float (*s_best)[HEAD_], int (*s_gbase)[HEAD_])
{
#define S_CAT(pp, d) s_u[(pp) * CATP_ + (d)]
    const int tid = threadIdx.x;
    const int b  = blockIdx.x;
    const int nn = b / (HW_ / P_);
    const int p0 = (b - nn * (HW_ / P_)) * P_;

    if (tid < P_ * HEAD_) {
        int pp = tid >> 2, h = tid & 3;
        int g = (nn * HW_ + p0 + pp) * HEAD_ + h;
        s_best[pp][h]  = ws_best[g];
        s_gbase[pp][h] = ws_gbase[g];
    }
    __syncthreads();

    if constexpr (TRANS) {
        for (int i = tid; i < P_ * 72; i += 256) {
            int px = i / 72, j = i - px * 72;
            int set = j / 24, jj = j - set * 24;        // ch = 4*jj
            int gb = s_gbase[px][jj / 6];               // head = (4*jj)/24
            float w[4] = {0.f, 0.f, 0.f, 0.f};
            if (gb >= 0) {
                const void* sp = (set == 0) ? s1 : (set == 1) ? s2 : s3;
                ld4w<BF16>(sp, gb + 4 * jj, w);
            }
            *((float4*)&S_CAT(px, set * C_ + 4 * jj)) = make_float4(w[0], w[1], w[2], w[3]);
        }
    } else {
        for (int i = tid; i < C3_ * P_; i += 256) {
            int pp = i / C3_, d = i - pp * C3_;
            int set = d / C_, ch = d - set * C_;
            int gb = s_gbase[pp][ch / HD_];
            float v = 0.f;
            if (gb >= 0) {
                const void* sp = (set == 0) ? s1 : (set == 1) ? s2 : s3;
                v = ld1<BF16>(sp, gb + ch * HW_);
            }
            S_CAT(pp, d) = v;
        }
    }
    __syncthreads();

    if (tid < 192) {
        const int cp = tid >> 2, pq = tid & 3;
        const int co0 = cp * 2, px0 = pq * 4;
        float acc[2][4];
        #pragma unroll
        for (int r = 0; r < 2; ++r)
            #pragma unroll
            for (int k = 0; k < 4; ++k) acc[r][k] = 0.f;
        for (int d = 0; d < C3_; d += 4) {
            float4 cv[4];
            #pragma unroll
            for (int k = 0; k < 4; ++k) cv[k] = *((const float4*)&S_CAT(px0 + k, d));
            #pragma unroll
            for (int r = 0; r < 2; ++r) {
                float w[4]; ld4w<BF16>(fw, (co0 + r) * C3_ + d, w);
                #pragma unroll
                for (int k = 0; k < 4; ++k)
                    acc[r][k] += w[0] * cv[k].x + w[1] * cv[k].y + w[2] * cv[k].z + w[3] * cv[k].w;
            }
        }
        const int hh = co0 / HD_;
        #pragma unroll
        for (int r = 0; r < 2; ++r) {
            float fbv = ld1<BF16>(fb, co0 + r);
            #pragma unroll
            for (int k = 0; k < 4; ++k)
                s_mid[px0 + k][co0 + r] = (acc[r][k] + fbv) * s_best[px0 + k][hh];
        }
    }
    __syncthreads();

    if (tid < 192) {
        const int dp = tid >> 2, pq = tid & 3;
        const int do0 = dp * 2, px0 = pq * 4;
        float acc[2][4];
        #pragma unroll
        for (int r = 0; r < 2; ++r)
            #pragma unroll
            for (int k = 0; k < 4; ++k) acc[r][k] = 0.f;
        for (int c = 0; c < C_; c += 4) {
            float4 mv[4];
            #pragma unroll
            for (int k = 0; k < 4; ++k) mv[k] = *((const float4*)&s_mid[px0 + k][c]);
            #pragma unroll
            for (int r = 0; r < 2; ++r) {
                float w[4]; ld4w<BF16>(pw, (do0 + r) * C_ + c, w);
                #pragma unroll
                for (int k = 0; k < 4; ++k)
                    acc[r][k] += w[0] * mv[k].x + w[1] * mv[k].y + w[2] * mv[k].z + w[3] * mv[k].w;
            }
        }
        #pragma unroll
        for (int r = 0; r < 2; ++r) {
            float pbv = ld1<BF16>(pb, do0 + r);
            float av[4];
            ld4w<BF16>(anchor, (nn * C_ + do0 + r) * HW_ + p0 + px0, av);
            float res[4];
            #pragma unroll
            for (int k = 0; k < 4; ++k) res[k] = acc[r][k] + pbv + av[k];
            st4w<BF16>(outp, (nn * C_ + do0 + r) * HW_ + p0 + px0, res);
        }
    }
#undef S_CAT
}

template<bool TRANS>
__global__ __launch_bounds__(256, 6) void catgemv_kernel(
    const void* __restrict__ curr, const void* __restrict__ anchor,
    const void* __restrict__ s1, const void* __restrict__ s2,
    const void* __restrict__ s3, const void* __restrict__ pw,
    const void* __restrict__ pb, const void* __restrict__ fw,
    const void* __restrict__ fb, void* __restrict__ outp,
    const float* __restrict__ ws_best, const int* __restrict__ ws_gbase)
{
    __shared__ __align__(16) float s_u[P_ * CATP_];   // 18.7 KB
    __shared__ __align__(16) float s_mid[P_][QP_];    // 6.4 KB
    __shared__ float s_best[P_][HEAD_];
    __shared__ int   s_gbase[P_][HEAD_];
    __shared__ int   s_flag;
    const bool bf = block_detect_bf16((const u32*)curr, threadIdx.x, &s_flag);
    if (bf) catgemv_body<true , TRANS>(anchor, s1, s2, s3, pw, pb, fw, fb, outp, ws_best, ws_gbase,
                                       s_u, s_mid, s_best, s_gbase);
    else    catgemv_body<false, TRANS>(anchor, s1, s2, s3, pw, pb, fw, fb, outp, ws_best, ws_gbase,
                                       s_u, s_mid, s_best, s_gbase);
}

// ====================== monolithic fallback (round-2 verbatim, scattered k) ======================
template<bool BF16>
__device__ __forceinline__ void mono_body(
    const void* __restrict__ curr, const void* __restrict__ idxf,
    const void* __restrict__ anchor, const void* __restrict__ s1,
    const void* __restrict__ s2, const void* __restrict__ s3,
    const void* __restrict__ loc, const void* __restrict__ pw,
    const void* __restrict__ pb, const void* __restrict__ fw,
    const void* __restrict__ fb, void* __restrict__ outp,
    float* s_u, float (*s_mid)[QP_], int (*s_lin)[P_], float (*s_red)[8],
    float (*s_best)[HEAD_], int (*s_bidx)[HEAD_], float* s_inv)
{
#define S_Q(pp, ch)  s_u[(pp) * QP_ + (ch)]
#define S_K(pp, ch)  s_u[P_ * QP_ + (pp) * QP_ + (ch)]
#define S_CAT(pp, d) s_u[(pp) * CATP_ + (d)]
    const int tid = threadIdx.x;
    const int b  = blockIdx.x;
    const int nn = b / (HW_ / P_);
    const int p0 = (b - nn * (HW_ / P_)) * P_;

    if (tid < T_ * P_) {
        int t = tid / P_, pp = tid - t * P_;
        int p = p0 + pp;
        float x = ld1<BF16>(loc, (nn * 2 * T_ + 2 * t    ) * HW_ + p);
        float y = ld1<BF16>(loc, (nn * 2 * T_ + 2 * t + 1) * HW_ + p);
        float gx = 2.0f * x / 95.0f - 1.0f;
        float gy = 2.0f * y / 95.0f - 1.0f;
        float fx = (gx + 1.0f) * 0.5f * 95.0f;
        float fy = (gy + 1.0f) * 0.5f * 95.0f;
        float ix = rintf(fx), iy = rintf(fy);
        bool v = (ix >= 0.0f) && (ix <= 95.0f) && (iy >= 0.0f) && (iy <= 95.0f);
        s_lin[t][pp] = v ? ((int)iy * W_ + (int)ix) : -1;
    }
    if (tid >= 128 && tid < 128 + P_ * HEAD_) {
        int q = tid - 128;
        s_best[q >> 2][q & 3] = -3.0e38f; s_bidx[q >> 2][q & 3] = 0;
    }
    for (int i = tid; i < C_ * (P_ / 4); i += 256) {
        int ch = i >> 2, pq = i & 3;
        float w[4];
        ld4w<BF16>(curr, (nn * C_ + ch) * HW_ + p0 + 4 * pq, w);
        S_Q(4 * pq + 0, ch) = w[0]; S_Q(4 * pq + 1, ch) = w[1];
        S_Q(4 * pq + 2, ch) = w[2]; S_Q(4 * pq + 3, ch) = w[3];
    }
    __syncthreads();
    if (tid < P_ * 8) {
        int pp = tid >> 3, j = tid & 7;
        float s = 0.f;
        #pragma unroll
        for (int k = 0; k < 12; ++k) { float v = S_Q(pp, j * 12 + k); s += v * v; }
        s_red[pp][j] = s;
    }
    __syncthreads();
    if (tid < P_) {
        float s = 0.f;
        #pragma unroll
        for (int j = 0; j < 8; ++j) s += s_red[tid][j];
        s_inv[tid] = 1.0f / fmaxf(sqrtf(s), 1e-12f);
    }
    __syncthreads();
    for (int i = tid; i < C_ * P_; i += 256) {
        int pp = i & (P_ - 1), ch = i >> 4;
        S_Q(pp, ch) *= s_inv[pp];
    }
    for (int t = 0; t < T_; ++t) {
        __syncthreads();
        for (int i = tid; i < C_ * P_; i += 256) {
            int ch = i / P_, pp = i - ch * P_;
            int lin = s_lin[t][pp];
            S_K(pp, ch) = (lin >= 0) ? ld1<BF16>(idxf, ((nn * T_ + t) * C_ + ch) * HW_ + lin) : 0.0f;
        }
        __syncthreads();
        if (tid < P_ * 8) {
            int pp = tid >> 3, j = tid & 7;
            float s = 0.f;
            #pragma unroll
            for (int k = 0; k < 12; ++k) { float v = S_K(pp, j * 12 + k); s += v * v; }
            s_red[pp][j] = s;
        }
        __syncthreads();
        if (tid < P_) {
            float s = 0.f;
            #pragma unroll
            for (int j = 0; j < 8; ++j) s += s_red[tid][j];
            s_inv[tid] = 1.0f / fmaxf(sqrtf(s), 1e-12f);
        }
        __syncthreads();
        if (tid < P_ * HEAD_) {
            int pp = tid >> 2, h = tid & 3;
            float s = 0.f;
            #pragma unroll
            for (int dq = 0; dq < 6; ++dq) {
                const float4 kv = *((const float4*)&S_K(pp, h * HD_ + 4 * dq));
                const float4 qv = *((const float4*)&S_Q(pp, h * HD_ + 4 * dq));
                s += kv.x * qv.x; s += kv.y * qv.y; s += kv.z * qv.z; s += kv.w * qv.w;
            }
            s *= s_inv[pp];
            if (s > s_best[pp][h]) { s_best[pp][h] = s; s_bidx[pp][h] = t; }
        }
    }
    __syncthreads();
    for (int i = tid; i < C3_ * P_; i += 256) {
        int pp = i / C3_, d = i - pp * C3_;
        int set = d / C_, ch = d - set * C_;
        int h = ch / HD_;
        int bt = s_bidx[pp][h];
        int lin = s_lin[bt][pp];
        float v = 0.f;
        if (lin >= 0) {
            const void* sp = (set == 0) ? s1 : (set == 1) ? s2 : s3;
            v = ld1<BF16>(sp, ((nn * T_ + bt) * C_ + ch) * HW_ + lin);
        }
        S_CAT(pp, d) = v;
    }
    __syncthreads();
    if (tid < 96) {
        const int cq = tid >> 2, pq = tid & 3;
        const int co0 = cq * 4, px0 = pq * 4;
        float acc[4][4];
        #pragma unroll
        for (int r = 0; r < 4; ++r)
            #pragma unroll
            for (int k = 0; k < 4; ++k) acc[r][k] = 0.f;
        for (int d = 0; d < C3_; d += 4) {
            float4 cv[4];
            #pragma unroll
            for (int k = 0; k < 4; ++k) cv[k] = *((const float4*)&S_CAT(px0 + k, d));
            #pragma unroll
            for (int r = 0; r < 4; ++r) {
                float w[4]; ld4w<BF16>(fw, (co0 + r) * C3_ + d, w);
                #pragma unroll
                for (int k = 0; k < 4; ++k)
                    acc[r][k] += w[0] * cv[k].x + w[1] * cv[k].y + w[2] * cv[k].z + w[3] * cv[k].w;
            }
        }
        const int hh = co0 / HD_;
        #pragma unroll
        for (int r = 0; r < 4; ++r) {
            float fbv = ld1<BF16>(fb, co0 + r);
            #pragma unroll
            for (int k = 0; k < 4; ++k)
                s_mid[px0 + k][co0 + r] = (acc[r][k] + fbv) * s_best[px0 + k][hh];
        }
    }
    __syncthreads();
    if (tid < 96) {
        const int dq = tid >> 2, pq = tid & 3;
        const int do0 = dq * 4, px0 = pq * 4;
        float acc[4][4];
        #pragma unroll
        for (int r = 0; r < 4; ++r)
            #pragma unroll
            for (int k = 0; k < 4; ++k) acc[r][k] = 0.f;
        for (int c = 0; c < C_; c += 4) {
            float4 mv[4];
            #pragma unroll
            for (int k = 0; k < 4; ++k) mv[k] = *((const float4*)&s_mid[px0 + k][c]);
            #pragma unroll
            for (int r = 0; r < 4; ++r) {
                float w[4]; ld4w<BF16>(pw, (do0 + r) * C_ + c, w);
                #pragma unroll
                for (int k = 0; k < 4; ++k)
                    acc[r][k] += w[0] * mv[k].x + w[1] * mv[k].y + w[2] * mv[k].z + w[3] * mv[k].w;
            }
        }
        #pragma unroll
        for (int r = 0; r < 4; ++r) {
            float pbv = ld1<BF16>(pb, do0 + r);
            float av[4];
            ld4w<BF16>(anchor, (nn * C_ + do0 + r) * HW_ + p0 + px0, av);
            float res[4];
            #pragma unroll
            for (int k = 0; k < 4; ++k) res[k] = acc[r][k] + pbv + av[k];
            st4w<BF16>(outp, (nn * C_ + do0 + r) * HW_ + p0 + px0, res);
        }
    }
#undef S_Q
#undef S_K
#undef S_CAT
}

__global__ __launch_bounds__(256) void mono_kernel(
    const void* __restrict__ curr, const void* __restrict__ idxf,
    const void* __restrict__ anchor, const void* __restrict__ s1,
    const void* __restrict__ s2, const void* __restrict__ s3,
    const void* __restrict__ loc, const void* __restrict__ pw,
    const void* __restrict__ pb, const void* __restrict__ fw,
    const void* __restrict__ fb, void* __restrict__ outp)
{
    __shared__ __align__(16) float s_u[P_ * CATP_];
    __shared__ __align__(16) float s_mid[P_][QP_];
    __shared__ int   s_lin[T_][P_];
    __shared__ float s_red[P_][8];
    __shared__ float s_best[P_][HEAD_];
    __shared__ int   s_bidx[P_][HEAD_];
    __shared__ float s_inv[P_];
    __shared__ int   s_flag;
    const bool bf = block_detect_bf16((const u32*)curr, threadIdx.x, &s_flag);
    if (bf) mono_body<true >(curr, idxf, anchor, s1, s2, s3, loc, pw, pb, fw, fb, outp,
                             s_u, s_mid, s_lin, s_red, s_best, s_bidx, s_inv);
    else    mono_body<false>(curr, idxf, anchor, s1, s2, s3, loc, pw, pb, fw, fb, outp,
                             s_u, s_mid, s_lin, s_red, s_best, s_bidx, s_inv);
}

extern "C" void kernel_launch(void* const* d_in, const int* in_sizes, int n_in,
                              void* d_out, int out_size, void* d_ws, size_t ws_size,
                              hipStream_t stream) {
    (void)in_sizes; (void)n_in; (void)out_size;
    const unsigned long long SZB  = (unsigned long long)N_ * T_ * HW_ * C_ * 4ull; // 49,545,216 (f32 worst case)
    const unsigned long long AUXB = (unsigned long long)N_ * HW_ * HEAD_ * 4ull;   // 294,912 B each
    char* wsb = (char*)d_ws;

    dim3 grid(NBLK_), block(256);
    if (ws_size >= 4 * SZB + 2 * AUXB) {
        // FULL mode: kT transpose -> fused(argmax || s123 transpose) -> catgemv
        void*  kT       = wsb;
        void*  s123T    = wsb + SZB;
        float* ws_best  = (float*)(wsb + 4 * SZB);
        int*   ws_gbase = (int*)  (wsb + 4 * SZB + AUXB);
        transp_kernel<<<dim3(TBLK_, 1), 256, 0, stream>>>(
            d_in[1], d_in[1], d_in[1], d_in[1], kT, SZB, (const u32*)d_in[0]);
        fused_kernel<<<dim3(NBLK_ + 3 * TBLK_), 256, 0, stream>>>(
            d_in[0], d_in[6], kT, d_in[3], d_in[4], d_in[5], s123T, SZB, ws_best, ws_gbase);
        catgemv_kernel<true><<<grid, block, 0, stream>>>(
            d_in[0], d_in[2],
            (char*)s123T, (char*)s123T + SZB, (char*)s123T + 2 * SZB,
            d_in[7], d_in[8], d_in[9], d_in[10], d_out, ws_best, ws_gbase);
    } else if (ws_size >= SZB + 2 * AUXB) {
        // kT-only mode
        void*  kT       = wsb;
        float* ws_best  = (float*)(wsb + SZB);
        int*   ws_gbase = (int*)  (wsb + SZB + AUXB);
        transp_kernel<<<dim3(TBLK_, 1), 256, 0, stream>>>(
            d_in[1], d_in[1], d_in[1], d_in[1], kT, SZB, (const u32*)d_in[0]);
        argmax_kernel<false><<<grid, block, 0, stream>>>(d_in[0], d_in[6], kT, ws_best, ws_gbase);
        catgemv_kernel<false><<<grid, block, 0, stream>>>(d_in[0], d_in[2], d_in[3], d_in[4], d_in[5],
                                                          d_in[7], d_in[8], d_in[9], d_in[10],
                                                          d_out, ws_best, ws_gbase);
    } else {
        mono_kernel<<<grid, block, 0, stream>>>(d_in[0], d_in[1], d_in[2], d_in[3], d_in[4],
                                                d_in[5], d_in[6], d_in[7], d_in[8], d_in[9],
                                                d_in[10], d_out);
    }
}